// Round 20
// baseline (289.442 us; speedup 1.0000x reference)
//
#include <hip/hip_runtime.h>
#include <hip/hip_fp16.h>

#define NG 1024
#define SCAN_B 1024
#define BSH2 9                   // 512 nodes per bin
#define GN 512                   // nodes per bin
#define MAXBIN 256               // max bins (N <= 131072)
#define NB2 256                  // histogram / scatter chunks
#define SCB 1024                 // histogram / scatter block size
#define TSZ 8192                 // scatter tile (entries)
#define TS2 8192                 // csr4b tile (entries)
#define PGR 64                   // pooled LDS graph-window size

// ---------------- generic scan stage A: per-block inclusive scan ------------
__global__ void k_scanA(const int* __restrict__ in, int* __restrict__ tmp,
                        int* __restrict__ part, int L) {
    __shared__ int s[SCAN_B];
    int gid = blockIdx.x * SCAN_B + threadIdx.x;
    s[threadIdx.x] = (gid < L) ? in[gid] : 0;
    __syncthreads();
    for (int off = 1; off < SCAN_B; off <<= 1) {
        int t = (threadIdx.x >= off) ? s[threadIdx.x - off] : 0;
        __syncthreads();
        s[threadIdx.x] += t;
        __syncthreads();
    }
    if (gid < L) tmp[gid] = s[threadIdx.x];
    if (threadIdx.x == SCAN_B - 1) part[blockIdx.x] = s[SCAN_B - 1];
}

// ---------------- generic scan stage B: exclusive scan of partials ----------
__global__ void k_scanB(int* __restrict__ part, int NB) {
    __shared__ int s[SCAN_B];
    int v = (threadIdx.x < NB) ? part[threadIdx.x] : 0;
    s[threadIdx.x] = v;
    __syncthreads();
    for (int off = 1; off < SCAN_B; off <<= 1) {
        int t = (threadIdx.x >= off) ? s[threadIdx.x - off] : 0;
        __syncthreads();
        s[threadIdx.x] += t;
        __syncthreads();
    }
    if (threadIdx.x < NB) part[threadIdx.x] = threadIdx.x ? s[threadIdx.x - 1] : 0;
}

// ------- apply: offT = exclusive scan; offT[L] = total; zero pooled/cnt -----
__global__ void k_applyT(const int* __restrict__ tmp2, const int* __restrict__ part2,
                         int* __restrict__ histT, int L,
                         float* __restrict__ pooled, float* __restrict__ cnt) {
    int k = blockIdx.x * blockDim.x + threadIdx.x;
    if (k < L) {
        int incl = tmp2[k] + part2[k >> 10];
        int orig = histT[k];
        histT[k] = incl - orig;
        if (k == L - 1) histT[L] = incl;
    }
    if (k < NG * 32) pooled[k] = 0.0f;
    if (k < NG) cnt[k] = 0.0f;
}

// ------- pass 1: per-chunk coarse-bin histogram (bin-major output) ----------
__global__ __launch_bounds__(SCB) void k_hist(const int* __restrict__ dst,
                                              int* __restrict__ histT,
                                              int E, int CH, int NBIN) {
    __shared__ int cnt_s[MAXBIN];
    if (threadIdx.x < MAXBIN) cnt_s[threadIdx.x] = 0;
    __syncthreads();
    int blk = blockIdx.x;
    int s0 = blk * CH, s1 = s0 + CH; if (s1 > E) s1 = E;
    for (int e = s0 + threadIdx.x; e < s1; e += SCB)
        atomicAdd(&cnt_s[dst[e] >> BSH2], 1);
    __syncthreads();
    for (int b = threadIdx.x; b < NBIN; b += SCB)
        histT[b * NB2 + blk] = cnt_s[b];
}

// ------- pass 2: tiled write-combining partition ----------------------------
__global__ __launch_bounds__(1024) void k_scatter(const int* __restrict__ src,
                                                  const int* __restrict__ dst,
                                                  const int* __restrict__ offT,
                                                  unsigned* __restrict__ binned,
                                                  int E, int CH, int NBIN) {
    __shared__ unsigned stg[TSZ];
    __shared__ unsigned char sbin[TSZ];
    __shared__ int th[MAXBIN];
    __shared__ int sc[MAXBIN];
    __shared__ int toff[MAXBIN + 1];
    __shared__ int gcur[MAXBIN];
    int tid = threadIdx.x;
    int blk = blockIdx.x;
    if (tid < MAXBIN) {
        th[tid] = 0;
        gcur[tid] = (tid < NBIN) ? offT[tid * NB2 + blk] : 0;
    }
    __syncthreads();
    int s0 = blk * CH, s1 = s0 + CH; if (s1 > E) s1 = E;
    for (int t0 = s0; t0 < s1; t0 += TSZ) {
        int cnt = s1 - t0; if (cnt > TSZ) cnt = TSZ;
        unsigned pk[8]; int rk[8]; int bn[8];
#pragma unroll
        for (int j = 0; j < 8; ++j) {
            int e = t0 + tid + j * 1024;
            bn[j] = -1;
            if (e < t0 + cnt) {
                int d = dst[e];
                int b = d >> BSH2;
                pk[j] = (unsigned)src[e] | ((unsigned)(d & (GN - 1)) << 17);
                bn[j] = b;
                rk[j] = atomicAdd(&th[b], 1);
            }
        }
        __syncthreads();
        if (tid < MAXBIN) sc[tid] = th[tid];
        __syncthreads();
        for (int off = 1; off < MAXBIN; off <<= 1) {
            int v = 0;
            if (tid < MAXBIN && tid >= off) v = sc[tid - off];
            __syncthreads();
            if (tid < MAXBIN) sc[tid] += v;
            __syncthreads();
        }
        if (tid < MAXBIN) toff[tid + 1] = sc[tid];
        if (tid == 0) toff[0] = 0;
        __syncthreads();
#pragma unroll
        for (int j = 0; j < 8; ++j)
            if (bn[j] >= 0) {
                int p = toff[bn[j]] + rk[j];
                stg[p] = pk[j];
                sbin[p] = (unsigned char)bn[j];
            }
        __syncthreads();
#pragma unroll 4
        for (int i = tid; i < cnt; i += 1024) {
            int b = sbin[i];
            binned[gcur[b] + (i - toff[b])] = stg[i];
        }
        __syncthreads();
        if (tid < MAXBIN) { gcur[tid] += th[tid]; th[tid] = 0; }
        __syncthreads();
    }
}

// ------- csr4a: per-bin degrees + prefix -> row_ptr, dinv, xd ---------------
__global__ __launch_bounds__(1024) void k_csr4a(
        const unsigned* __restrict__ binned, const int* __restrict__ offT,
        int* __restrict__ row_ptr, float* __restrict__ dinv,
        const float* __restrict__ x, float4* __restrict__ xd, int N, int NBIN) {
    __shared__ int cnt[GN];
    __shared__ int pre[GN];
    int tid = threadIdx.x;
    int b = blockIdx.x;
    int base = offT[b * NB2];
    int end  = offT[(b + 1) * NB2];
    if (tid < GN) cnt[tid] = 0;
    __syncthreads();
    for (int i = base + tid; i < end; i += 1024)
        atomicAdd(&cnt[(binned[i] >> 17) & (GN - 1)], 1);
    __syncthreads();
    if (tid < GN) pre[tid] = cnt[tid];
    __syncthreads();
    for (int off = 1; off < GN; off <<= 1) {
        int v = 0;
        if (tid < GN && tid >= off) v = pre[tid - off];
        __syncthreads();
        if (tid < GN) pre[tid] += v;
        __syncthreads();
    }
    int gv = (b << BSH2) + tid;
    if (tid < GN && gv < N) {
        row_ptr[gv] = base + pre[tid] - cnt[tid];
        float d = rsqrtf((float)cnt[tid] + 1.0f);        // +1 self-loop
        dinv[gv] = d;
        xd[gv] = make_float4(d * x[gv * 3 + 0], d * x[gv * 3 + 1],
                             d * x[gv * 3 + 2], 0.0f);
    }
    if (b == NBIN - 1 && tid == 0) row_ptr[N] = end;
}

// ------- csr4b: tiled placement + FUSED layer-1 aggregation + matmul --------
// Per edge: rank for write-combined csr placement AND gather xd[src] into
// per-bin LDS accumulators. Epilogue: g1h = fp16(dinv * relu(dinv*(sum) W1+b1)).
__global__ __launch_bounds__(1024) void k_csr4b(
        const unsigned* __restrict__ binned, const int* __restrict__ offT,
        const int* __restrict__ row_ptr, const float* __restrict__ dinv,
        const float4* __restrict__ xd, const float* __restrict__ W1,
        const float* __restrict__ b1, int* __restrict__ csr,
        __half* __restrict__ g1h, int N, int NBIN) {
    __shared__ unsigned stg[TS2];
    __shared__ int rp[GN];
    __shared__ int run[GN];
    __shared__ int th[GN];
    __shared__ int toff[GN + 1];
    __shared__ float xax[GN];
    __shared__ float xay[GN];
    __shared__ float xaz[GN];
    __shared__ float sW[48];
    __shared__ float sb[16];
    int tid = threadIdx.x;
    int b = blockIdx.x;
    int base = offT[b * NB2];
    int end  = offT[(b + 1) * NB2];
    int first = b << BSH2;
    if (tid < 48) sW[tid] = W1[tid];
    if (tid < 16) sb[tid] = b1[tid];
    if (tid < GN) {
        int gv = first + tid;
        rp[tid] = (gv < N) ? row_ptr[gv] : end;
        run[tid] = 0; th[tid] = 0;
        xax[tid] = 0.0f; xay[tid] = 0.0f; xaz[tid] = 0.0f;
    }
    __syncthreads();
    for (int t0 = base; t0 < end; t0 += TS2) {
        int tc = end - t0; if (tc > TS2) tc = TS2;
        unsigned pk[8]; int rk[8], dl[8]; float4 xs[8];
#pragma unroll
        for (int j = 0; j < 8; ++j) {
            int e = t0 + tid + j * 1024;
            dl[j] = -1;
            if (e < t0 + tc) {
                unsigned p = binned[e];
                pk[j] = p;
                dl[j] = (int)((p >> 17) & (GN - 1));
                rk[j] = atomicAdd(&th[dl[j]], 1);
                xs[j] = xd[p & 0x1FFFFu];              // layer-1 gather (fused)
            }
        }
#pragma unroll
        for (int j = 0; j < 8; ++j)
            if (dl[j] >= 0) {
                atomicAdd(&xax[dl[j]], xs[j].x);
                atomicAdd(&xay[dl[j]], xs[j].y);
                atomicAdd(&xaz[dl[j]], xs[j].z);
            }
        __syncthreads();
        if (tid < GN) toff[tid + 1] = th[tid];
        if (tid == 0) toff[0] = 0;
        __syncthreads();
        for (int off = 1; off < GN; off <<= 1) {
            int v = 0;
            if (tid < GN && tid + 1 > off) v = toff[tid + 1 - off];
            __syncthreads();
            if (tid < GN) toff[tid + 1] += v;
            __syncthreads();
        }
#pragma unroll
        for (int j = 0; j < 8; ++j)
            if (dl[j] >= 0) stg[toff[dl[j]] + rk[j]] = pk[j];
        __syncthreads();
#pragma unroll 4
        for (int i = tid; i < tc; i += 1024) {
            unsigned p = stg[i];
            int d = (int)((p >> 17) & (GN - 1));
            csr[rp[d] + run[d] + (i - toff[d])] = (int)(p & 0x1FFFFu);
        }
        __syncthreads();
        if (tid < GN) { run[tid] += th[tid]; th[tid] = 0; }
        __syncthreads();
    }
    // epilogue: layer-1 matmul + relu for this bin's nodes
    if (tid < GN) {
        int gv = first + tid;
        if (gv < N) {
            float4 self = xd[gv];
            float sx = xax[tid] + self.x;
            float sy = xay[tid] + self.y;
            float sz = xaz[tid] + self.z;
            float d = dinv[gv];
#pragma unroll
            for (int f0 = 0; f0 < 16; f0 += 2) {
                float h0 = fmaxf(d * (sx * sW[f0]     + sy * sW[16 + f0]     + sz * sW[32 + f0])     + sb[f0],     0.0f);
                float h1 = fmaxf(d * (sx * sW[f0 + 1] + sy * sW[16 + f0 + 1] + sz * sW[32 + f0 + 1]) + sb[f0 + 1], 0.0f);
                __half2 p = __halves2half2(__float2half(d * h0), __float2half(d * h1));
                *(unsigned*)(g1h + (size_t)gv * 16 + f0) = *(unsigned*)&p;
            }
        }
    }
}

// ------- layer 2: fp16 gather (8 lanes/node, full 32B row per lane), --------
// matmul after aggregation, LDS-aggregated mean-pool. (unroll 4 = best)
__global__ __launch_bounds__(256) void k_gb(const int* __restrict__ row_ptr,
                                            const int* __restrict__ csr,
                                            const __half* __restrict__ g1h,
                                            const float* __restrict__ dinv,
                                            const float* __restrict__ W2,
                                            const float* __restrict__ b2,
                                            const int* __restrict__ batch,
                                            float* __restrict__ pooled,
                                            float* __restrict__ cnt, int N) {
    __shared__ float sW[512];
    __shared__ float sb[32];
    __shared__ float sacc[PGR * 32];
    __shared__ int   scnt[PGR];
    __shared__ int   sgf;
    int t = threadIdx.x;
    for (int i = t; i < 512; i += 256) sW[i] = W2[i];
    if (t < 32) sb[t] = b2[t];
    for (int i = t; i < PGR * 32; i += 256) sacc[i] = 0.0f;
    if (t < PGR) scnt[t] = 0;
    int v0 = blockIdx.x * 32;                 // 32 nodes per block (8 lanes each)
    if (t == 0) sgf = (v0 < N) ? batch[v0] : 0;
    __syncthreads();
    int gt = blockIdx.x * blockDim.x + t;
    int v = gt >> 3, l = gt & 7;
    int gfirst = sgf;
    if (v < N) {
        const uint4* g4 = (const uint4*)g1h;  // 2 uint4 per node row
        float s16[16];
#pragma unroll
        for (int j = 0; j < 16; ++j) s16[j] = 0.0f;
        int beg = row_ptr[v], end = row_ptr[v + 1];
#pragma unroll 4
        for (int e = beg + l; e < end; e += 8) {
            int s = csr[e];
            uint4 lo = g4[(size_t)s * 2];
            uint4 hi = g4[(size_t)s * 2 + 1];
            float2 f;
            f = __half22float2(*(__half2*)&lo.x); s16[0]  += f.x; s16[1]  += f.y;
            f = __half22float2(*(__half2*)&lo.y); s16[2]  += f.x; s16[3]  += f.y;
            f = __half22float2(*(__half2*)&lo.z); s16[4]  += f.x; s16[5]  += f.y;
            f = __half22float2(*(__half2*)&lo.w); s16[6]  += f.x; s16[7]  += f.y;
            f = __half22float2(*(__half2*)&hi.x); s16[8]  += f.x; s16[9]  += f.y;
            f = __half22float2(*(__half2*)&hi.y); s16[10] += f.x; s16[11] += f.y;
            f = __half22float2(*(__half2*)&hi.z); s16[12] += f.x; s16[13] += f.y;
            f = __half22float2(*(__half2*)&hi.w); s16[14] += f.x; s16[15] += f.y;
        }
        if (l == 0) {                         // self-loop
            uint4 lo = g4[(size_t)v * 2];
            uint4 hi = g4[(size_t)v * 2 + 1];
            float2 f;
            f = __half22float2(*(__half2*)&lo.x); s16[0]  += f.x; s16[1]  += f.y;
            f = __half22float2(*(__half2*)&lo.y); s16[2]  += f.x; s16[3]  += f.y;
            f = __half22float2(*(__half2*)&lo.z); s16[4]  += f.x; s16[5]  += f.y;
            f = __half22float2(*(__half2*)&lo.w); s16[6]  += f.x; s16[7]  += f.y;
            f = __half22float2(*(__half2*)&hi.x); s16[8]  += f.x; s16[9]  += f.y;
            f = __half22float2(*(__half2*)&hi.y); s16[10] += f.x; s16[11] += f.y;
            f = __half22float2(*(__half2*)&hi.z); s16[12] += f.x; s16[13] += f.y;
            f = __half22float2(*(__half2*)&hi.w); s16[14] += f.x; s16[15] += f.y;
        }
#pragma unroll
        for (int j = 0; j < 16; ++j) {
            s16[j] += __shfl_xor(s16[j], 1, 64);
            s16[j] += __shfl_xor(s16[j], 2, 64);
            s16[j] += __shfl_xor(s16[j], 4, 64);
        }
        float d = dinv[v];
        int g = batch[v];
        int gl = g - gfirst;
        int f0 = l * 4;
#pragma unroll
        for (int j = 0; j < 4; ++j) {
            float acc = 0.0f;
#pragma unroll
            for (int k = 0; k < 16; ++k) acc += s16[k] * sW[k * 32 + f0 + j];
            float h = fmaxf(d * acc + sb[f0 + j], 0.0f);
            if (gl < PGR) atomicAdd(&sacc[gl * 32 + f0 + j], h);
            else          atomicAdd(&pooled[g * 32 + f0 + j], h);
        }
        if (l == 0) {
            if (gl < PGR) atomicAdd(&scnt[gl], 1);
            else          atomicAdd(&cnt[g], 1.0f);
        }
    }
    __syncthreads();
    for (int i = t; i < PGR * 32; i += 256) {
        float val = sacc[i];
        if (val != 0.0f) atomicAdd(&pooled[(gfirst + (i >> 5)) * 32 + (i & 31)], val);
    }
    for (int i = t; i < PGR; i += 256) {
        int c = scnt[i];
        if (c) atomicAdd(&cnt[gfirst + i], (float)c);
    }
}

// ------- final linear head ---------------------------------------------------
__global__ void k_out(const float* __restrict__ pooled, const float* __restrict__ cnt,
                      const float* __restrict__ Wl, const float* __restrict__ bl,
                      float* __restrict__ out) {
    int t = blockIdx.x * blockDim.x + threadIdx.x;
    if (t >= NG * 3) return;
    int g = t / 3, c = t % 3;
    float inv = 1.0f / fmaxf(cnt[g], 1.0f);
    float s = bl[c];
#pragma unroll
    for (int f = 0; f < 32; ++f) s += pooled[g * 32 + f] * inv * Wl[f * 3 + c];
    out[g * 3 + c] = s;
}

extern "C" void kernel_launch(void* const* d_in, const int* in_sizes, int n_in,
                              void* d_out, int out_size, void* d_ws, size_t ws_size,
                              hipStream_t stream) {
    const float* x     = (const float*)d_in[0];
    const int*   ei    = (const int*)d_in[1];
    const int*   batch = (const int*)d_in[2];
    const float* W1    = (const float*)d_in[3];
    const float* b1    = (const float*)d_in[4];
    const float* W2    = (const float*)d_in[5];
    const float* b2    = (const float*)d_in[6];
    const float* Wl    = (const float*)d_in[7];
    const float* bl    = (const float*)d_in[8];

    const int N = in_sizes[0] / 3;
    const int E = in_sizes[1] / 2;
    const int* src = ei;
    const int* dst = ei + E;
    const int NBIN = (N + GN - 1) >> BSH2;        // coarse bins (<= 256)
    const int CH   = (E + NB2 - 1) / NB2;         // edges per chunk
    const int L    = NBIN * NB2;                  // histogram length

    char* w = (char*)d_ws;
    int*      row_ptr = (int*)w;      w += (size_t)(N + 4) * 4;
    float*    dinv    = (float*)w;    w += (size_t)N * 4;
    int*      histT   = (int*)w;      w += (size_t)(L + 4) * 4;  // +1 total slot
    int*      tmp2    = (int*)w;      w += (size_t)L * 4;
    int*      part2   = (int*)w;      w += (size_t)SCAN_B * 4;
    unsigned* binned  = (unsigned*)w; w += (size_t)(E + 16) * 4;
    int*      csr     = (int*)w;      w += (size_t)E * 4;
    float4*   xd      = (float4*)w;   w += (size_t)N * 16;
    __half*   g1h     = (__half*)w;   w += ((size_t)N * 32 + 15) & ~(size_t)15;
    float*    pooled  = (float*)w;    w += (size_t)NG * 32 * 4;
    float*    cnt     = (float*)w;    w += (size_t)NG * 4;

    const int B = 256;
    const int NBl = (L + SCAN_B - 1) / SCAN_B;

    k_hist<<<NB2, SCB, 0, stream>>>(dst, histT, E, CH, NBIN);
    k_scanA<<<NBl, SCAN_B, 0, stream>>>(histT, tmp2, part2, L);
    k_scanB<<<1, SCAN_B, 0, stream>>>(part2, NBl);
    k_applyT<<<(L + B - 1) / B, B, 0, stream>>>(tmp2, part2, histT, L, pooled, cnt);
    k_scatter<<<NB2, 1024, 0, stream>>>(src, dst, histT, binned, E, CH, NBIN);
    k_csr4a<<<NBIN, 1024, 0, stream>>>(binned, histT, row_ptr, dinv, x, xd, N, NBIN);
    k_csr4b<<<NBIN, 1024, 0, stream>>>(binned, histT, row_ptr, dinv, xd, W1, b1,
                                       csr, g1h, N, NBIN);
    k_gb<<<((size_t)N * 8 + B - 1) / B, B, 0, stream>>>(row_ptr, csr, g1h, dinv, W2, b2, batch,
                                                        pooled, cnt, N);
    k_out<<<(NG * 3 + B - 1) / B, B, 0, stream>>>(pooled, cnt, Wl, bl, (float*)d_out);
}

// Round 21
// 175.156 us; speedup vs baseline: 1.6525x; 1.6525x over previous
//
#include <hip/hip_runtime.h>
#include <hip/hip_fp16.h>

#define NG 1024
#define SCAN_B 1024
#define BSH2 9                   // 512 nodes per bin
#define GN 512                   // nodes per bin
#define MAXBIN 256               // max bins (N <= 131072)
#define NB2 256                  // histogram / scatter chunks
#define SCB 1024                 // histogram / scatter block size
#define TSZ 8192                 // scatter tile (entries)
#define TS2 8192                 // csr4 tile (entries)
#define PGR 64                   // pooled LDS graph-window size

// ---------------- generic scan stage A: per-block inclusive scan ------------
__global__ void k_scanA(const int* __restrict__ in, int* __restrict__ tmp,
                        int* __restrict__ part, int L) {
    __shared__ int s[SCAN_B];
    int gid = blockIdx.x * SCAN_B + threadIdx.x;
    s[threadIdx.x] = (gid < L) ? in[gid] : 0;
    __syncthreads();
    for (int off = 1; off < SCAN_B; off <<= 1) {
        int t = (threadIdx.x >= off) ? s[threadIdx.x - off] : 0;
        __syncthreads();
        s[threadIdx.x] += t;
        __syncthreads();
    }
    if (gid < L) tmp[gid] = s[threadIdx.x];
    if (threadIdx.x == SCAN_B - 1) part[blockIdx.x] = s[SCAN_B - 1];
}

// ---------------- generic scan stage B: exclusive scan of partials ----------
__global__ void k_scanB(int* __restrict__ part, int NB) {
    __shared__ int s[SCAN_B];
    int v = (threadIdx.x < NB) ? part[threadIdx.x] : 0;
    s[threadIdx.x] = v;
    __syncthreads();
    for (int off = 1; off < SCAN_B; off <<= 1) {
        int t = (threadIdx.x >= off) ? s[threadIdx.x - off] : 0;
        __syncthreads();
        s[threadIdx.x] += t;
        __syncthreads();
    }
    if (threadIdx.x < NB) part[threadIdx.x] = threadIdx.x ? s[threadIdx.x - 1] : 0;
}

// ------- apply: offT = exclusive scan; offT[L] = total; zero pooled/cnt -----
__global__ void k_applyT(const int* __restrict__ tmp2, const int* __restrict__ part2,
                         int* __restrict__ histT, int L,
                         float* __restrict__ pooled, float* __restrict__ cnt) {
    int k = blockIdx.x * blockDim.x + threadIdx.x;
    if (k < L) {
        int incl = tmp2[k] + part2[k >> 10];
        int orig = histT[k];
        histT[k] = incl - orig;
        if (k == L - 1) histT[L] = incl;
    }
    if (k < NG * 32) pooled[k] = 0.0f;
    if (k < NG) cnt[k] = 0.0f;
}

// ------- pass 1: per-chunk coarse-bin histogram (bin-major output) ----------
__global__ __launch_bounds__(SCB) void k_hist(const int* __restrict__ dst,
                                              int* __restrict__ histT,
                                              int E, int CH, int NBIN) {
    __shared__ int cnt_s[MAXBIN];
    if (threadIdx.x < MAXBIN) cnt_s[threadIdx.x] = 0;
    __syncthreads();
    int blk = blockIdx.x;
    int s0 = blk * CH, s1 = s0 + CH; if (s1 > E) s1 = E;
    for (int e = s0 + threadIdx.x; e < s1; e += SCB)
        atomicAdd(&cnt_s[dst[e] >> BSH2], 1);
    __syncthreads();
    for (int b = threadIdx.x; b < NBIN; b += SCB)
        histT[b * NB2 + blk] = cnt_s[b];
}

// ------- pass 2: tiled write-combining partition ----------------------------
__global__ __launch_bounds__(1024) void k_scatter(const int* __restrict__ src,
                                                  const int* __restrict__ dst,
                                                  const int* __restrict__ offT,
                                                  unsigned* __restrict__ binned,
                                                  int E, int CH, int NBIN) {
    __shared__ unsigned stg[TSZ];
    __shared__ unsigned char sbin[TSZ];
    __shared__ int th[MAXBIN];
    __shared__ int sc[MAXBIN];
    __shared__ int toff[MAXBIN + 1];
    __shared__ int gcur[MAXBIN];
    int tid = threadIdx.x;
    int blk = blockIdx.x;
    if (tid < MAXBIN) {
        th[tid] = 0;
        gcur[tid] = (tid < NBIN) ? offT[tid * NB2 + blk] : 0;
    }
    __syncthreads();
    int s0 = blk * CH, s1 = s0 + CH; if (s1 > E) s1 = E;
    for (int t0 = s0; t0 < s1; t0 += TSZ) {
        int cnt = s1 - t0; if (cnt > TSZ) cnt = TSZ;
        unsigned pk[8]; int rk[8]; int bn[8];
#pragma unroll
        for (int j = 0; j < 8; ++j) {
            int e = t0 + tid + j * 1024;
            bn[j] = -1;
            if (e < t0 + cnt) {
                int d = dst[e];
                int b = d >> BSH2;
                pk[j] = (unsigned)src[e] | ((unsigned)(d & (GN - 1)) << 17);
                bn[j] = b;
                rk[j] = atomicAdd(&th[b], 1);
            }
        }
        __syncthreads();
        if (tid < MAXBIN) sc[tid] = th[tid];
        __syncthreads();
        for (int off = 1; off < MAXBIN; off <<= 1) {
            int v = 0;
            if (tid < MAXBIN && tid >= off) v = sc[tid - off];
            __syncthreads();
            if (tid < MAXBIN) sc[tid] += v;
            __syncthreads();
        }
        if (tid < MAXBIN) toff[tid + 1] = sc[tid];
        if (tid == 0) toff[0] = 0;
        __syncthreads();
#pragma unroll
        for (int j = 0; j < 8; ++j)
            if (bn[j] >= 0) {
                int p = toff[bn[j]] + rk[j];
                stg[p] = pk[j];
                sbin[p] = (unsigned char)bn[j];
            }
        __syncthreads();
#pragma unroll 4
        for (int i = tid; i < cnt; i += 1024) {
            int b = sbin[i];
            binned[gcur[b] + (i - toff[b])] = stg[i];
        }
        __syncthreads();
        if (tid < MAXBIN) { gcur[tid] += th[tid]; th[tid] = 0; }
        __syncthreads();
    }
}

// ------- per-bin tiled write-combining sort: binned -> csr ------------------
__global__ __launch_bounds__(1024) void k_csr4(
        const unsigned* __restrict__ binned, const int* __restrict__ offT,
        int* __restrict__ row_ptr, float* __restrict__ dinv,
        const float* __restrict__ x, float4* __restrict__ xd,
        int* __restrict__ csr, int N, int NBIN) {
    __shared__ unsigned stg[TS2];
    __shared__ unsigned short sdl[TS2];
    __shared__ int cnt[GN];
    __shared__ int pre[GN];
    __shared__ int run[GN];
    __shared__ int th[GN];
    __shared__ int toff[GN + 1];
    int tid = threadIdx.x;
    int b = blockIdx.x;
    int base = offT[b * NB2];
    int end  = offT[(b + 1) * NB2];
    if (tid < GN) cnt[tid] = 0;
    __syncthreads();
    for (int i = base + tid; i < end; i += 1024)
        atomicAdd(&cnt[(binned[i] >> 17) & (GN - 1)], 1);
    __syncthreads();
    if (tid < GN) pre[tid] = cnt[tid];
    __syncthreads();
    for (int off = 1; off < GN; off <<= 1) {
        int v = 0;
        if (tid < GN && tid >= off) v = pre[tid - off];
        __syncthreads();
        if (tid < GN) pre[tid] += v;
        __syncthreads();
    }
    int gv = (b << BSH2) + tid;
    if (tid < GN) {
        pre[tid] -= cnt[tid];             // exclusive
        run[tid] = 0;
        th[tid] = 0;
        if (gv < N) {
            row_ptr[gv] = base + pre[tid];
            float d = rsqrtf((float)cnt[tid] + 1.0f);    // +1 self-loop
            dinv[gv] = d;
            xd[gv] = make_float4(d * x[gv * 3 + 0], d * x[gv * 3 + 1],
                                 d * x[gv * 3 + 2], 0.0f);
        }
    }
    if (b == NBIN - 1 && tid == 0) row_ptr[N] = end;
    __syncthreads();
    for (int t0 = base; t0 < end; t0 += TS2) {
        int tc = end - t0; if (tc > TS2) tc = TS2;
        unsigned pk[8]; int rk[8], dl[8];
#pragma unroll
        for (int j = 0; j < 8; ++j) {
            int e = t0 + tid + j * 1024;
            dl[j] = -1;
            if (e < t0 + tc) {
                unsigned p = binned[e];
                pk[j] = p;
                dl[j] = (int)((p >> 17) & (GN - 1));
                rk[j] = atomicAdd(&th[dl[j]], 1);
            }
        }
        __syncthreads();
        if (tid < GN) toff[tid + 1] = th[tid];
        if (tid == 0) toff[0] = 0;
        __syncthreads();
        for (int off = 1; off < GN; off <<= 1) {
            int v = 0;
            if (tid < GN && tid + 1 > off) v = toff[tid + 1 - off];
            __syncthreads();
            if (tid < GN) toff[tid + 1] += v;
            __syncthreads();
        }
#pragma unroll
        for (int j = 0; j < 8; ++j)
            if (dl[j] >= 0) {
                int p = toff[dl[j]] + rk[j];
                stg[p] = pk[j];
                sdl[p] = (unsigned short)dl[j];
            }
        __syncthreads();
#pragma unroll 4
        for (int i = tid; i < tc; i += 1024) {
            int d = sdl[i];
            csr[base + pre[d] + run[d] + (i - toff[d])] = (int)(stg[i] & 0x1FFFFu);
        }
        __syncthreads();
        if (tid < GN) { run[tid] += th[tid]; th[tid] = 0; }
        __syncthreads();
    }
}

// ------- layer 1: gather xd (8-way edge split), matmul after aggregation ----
__global__ __launch_bounds__(256) void k_ga(const int* __restrict__ row_ptr,
                                            const int* __restrict__ csr,
                                            const float4* __restrict__ xd,
                                            const float* __restrict__ dinv,
                                            const float* __restrict__ W1,
                                            const float* __restrict__ b1,
                                            __half* __restrict__ g1h, int N) {
    __shared__ float sW[48];
    __shared__ float sb[16];
    if (threadIdx.x < 48) sW[threadIdx.x] = W1[threadIdx.x];
    if (threadIdx.x < 16) sb[threadIdx.x] = b1[threadIdx.x];
    __syncthreads();
    int t = blockIdx.x * blockDim.x + threadIdx.x;
    int v = t >> 3, l = t & 7;
    if (v >= N) return;
    int beg = row_ptr[v], end = row_ptr[v + 1];
    float sx = 0.0f, sy = 0.0f, sz = 0.0f;
#pragma unroll 8
    for (int e = beg + l; e < end; e += 8) {
        float4 a = xd[csr[e]];
        sx += a.x; sy += a.y; sz += a.z;
    }
    sx += __shfl_xor(sx, 1, 64); sy += __shfl_xor(sy, 1, 64); sz += __shfl_xor(sz, 1, 64);
    sx += __shfl_xor(sx, 2, 64); sy += __shfl_xor(sy, 2, 64); sz += __shfl_xor(sz, 2, 64);
    sx += __shfl_xor(sx, 4, 64); sy += __shfl_xor(sy, 4, 64); sz += __shfl_xor(sz, 4, 64);
    float4 self = xd[v];
    sx += self.x; sy += self.y; sz += self.z;
    float d = dinv[v];
    int f0 = l * 2;
    float h0 = fmaxf(d * (sx * sW[f0]     + sy * sW[16 + f0]     + sz * sW[32 + f0])     + sb[f0],     0.0f);
    float h1 = fmaxf(d * (sx * sW[f0 + 1] + sy * sW[16 + f0 + 1] + sz * sW[32 + f0 + 1]) + sb[f0 + 1], 0.0f);
    __half2 p = __halves2half2(__float2half(d * h0), __float2half(d * h1));
    *(unsigned*)(g1h + (size_t)v * 16 + f0) = *(unsigned*)&p;
}

// ------- layer 2: fp16 gather (8 lanes/node, full 32B row per lane), --------
// matmul after aggregation, LDS-aggregated mean-pool. (unroll 4 = best)
__global__ __launch_bounds__(256) void k_gb(const int* __restrict__ row_ptr,
                                            const int* __restrict__ csr,
                                            const __half* __restrict__ g1h,
                                            const float* __restrict__ dinv,
                                            const float* __restrict__ W2,
                                            const float* __restrict__ b2,
                                            const int* __restrict__ batch,
                                            float* __restrict__ pooled,
                                            float* __restrict__ cnt, int N) {
    __shared__ float sW[512];
    __shared__ float sb[32];
    __shared__ float sacc[PGR * 32];
    __shared__ int   scnt[PGR];
    __shared__ int   sgf;
    int t = threadIdx.x;
    for (int i = t; i < 512; i += 256) sW[i] = W2[i];
    if (t < 32) sb[t] = b2[t];
    for (int i = t; i < PGR * 32; i += 256) sacc[i] = 0.0f;
    if (t < PGR) scnt[t] = 0;
    int v0 = blockIdx.x * 32;                 // 32 nodes per block (8 lanes each)
    if (t == 0) sgf = (v0 < N) ? batch[v0] : 0;
    __syncthreads();
    int gt = blockIdx.x * blockDim.x + t;
    int v = gt >> 3, l = gt & 7;
    int gfirst = sgf;
    if (v < N) {
        const uint4* g4 = (const uint4*)g1h;  // 2 uint4 per node row
        float s16[16];
#pragma unroll
        for (int j = 0; j < 16; ++j) s16[j] = 0.0f;
        int beg = row_ptr[v], end = row_ptr[v + 1];
#pragma unroll 4
        for (int e = beg + l; e < end; e += 8) {
            int s = csr[e];
            uint4 lo = g4[(size_t)s * 2];
            uint4 hi = g4[(size_t)s * 2 + 1];
            float2 f;
            f = __half22float2(*(__half2*)&lo.x); s16[0]  += f.x; s16[1]  += f.y;
            f = __half22float2(*(__half2*)&lo.y); s16[2]  += f.x; s16[3]  += f.y;
            f = __half22float2(*(__half2*)&lo.z); s16[4]  += f.x; s16[5]  += f.y;
            f = __half22float2(*(__half2*)&lo.w); s16[6]  += f.x; s16[7]  += f.y;
            f = __half22float2(*(__half2*)&hi.x); s16[8]  += f.x; s16[9]  += f.y;
            f = __half22float2(*(__half2*)&hi.y); s16[10] += f.x; s16[11] += f.y;
            f = __half22float2(*(__half2*)&hi.z); s16[12] += f.x; s16[13] += f.y;
            f = __half22float2(*(__half2*)&hi.w); s16[14] += f.x; s16[15] += f.y;
        }
        if (l == 0) {                         // self-loop
            uint4 lo = g4[(size_t)v * 2];
            uint4 hi = g4[(size_t)v * 2 + 1];
            float2 f;
            f = __half22float2(*(__half2*)&lo.x); s16[0]  += f.x; s16[1]  += f.y;
            f = __half22float2(*(__half2*)&lo.y); s16[2]  += f.x; s16[3]  += f.y;
            f = __half22float2(*(__half2*)&lo.z); s16[4]  += f.x; s16[5]  += f.y;
            f = __half22float2(*(__half2*)&lo.w); s16[6]  += f.x; s16[7]  += f.y;
            f = __half22float2(*(__half2*)&hi.x); s16[8]  += f.x; s16[9]  += f.y;
            f = __half22float2(*(__half2*)&hi.y); s16[10] += f.x; s16[11] += f.y;
            f = __half22float2(*(__half2*)&hi.z); s16[12] += f.x; s16[13] += f.y;
            f = __half22float2(*(__half2*)&hi.w); s16[14] += f.x; s16[15] += f.y;
        }
#pragma unroll
        for (int j = 0; j < 16; ++j) {
            s16[j] += __shfl_xor(s16[j], 1, 64);
            s16[j] += __shfl_xor(s16[j], 2, 64);
            s16[j] += __shfl_xor(s16[j], 4, 64);
        }
        float d = dinv[v];
        int g = batch[v];
        int gl = g - gfirst;
        int f0 = l * 4;
#pragma unroll
        for (int j = 0; j < 4; ++j) {
            float acc = 0.0f;
#pragma unroll
            for (int k = 0; k < 16; ++k) acc += s16[k] * sW[k * 32 + f0 + j];
            float h = fmaxf(d * acc + sb[f0 + j], 0.0f);
            if (gl < PGR) atomicAdd(&sacc[gl * 32 + f0 + j], h);
            else          atomicAdd(&pooled[g * 32 + f0 + j], h);
        }
        if (l == 0) {
            if (gl < PGR) atomicAdd(&scnt[gl], 1);
            else          atomicAdd(&cnt[g], 1.0f);
        }
    }
    __syncthreads();
    for (int i = t; i < PGR * 32; i += 256) {
        float val = sacc[i];
        if (val != 0.0f) atomicAdd(&pooled[(gfirst + (i >> 5)) * 32 + (i & 31)], val);
    }
    for (int i = t; i < PGR; i += 256) {
        int c = scnt[i];
        if (c) atomicAdd(&cnt[gfirst + i], (float)c);
    }
}

// ------- final linear head ---------------------------------------------------
__global__ void k_out(const float* __restrict__ pooled, const float* __restrict__ cnt,
                      const float* __restrict__ Wl, const float* __restrict__ bl,
                      float* __restrict__ out) {
    int t = blockIdx.x * blockDim.x + threadIdx.x;
    if (t >= NG * 3) return;
    int g = t / 3, c = t % 3;
    float inv = 1.0f / fmaxf(cnt[g], 1.0f);
    float s = bl[c];
#pragma unroll
    for (int f = 0; f < 32; ++f) s += pooled[g * 32 + f] * inv * Wl[f * 3 + c];
    out[g * 3 + c] = s;
}

extern "C" void kernel_launch(void* const* d_in, const int* in_sizes, int n_in,
                              void* d_out, int out_size, void* d_ws, size_t ws_size,
                              hipStream_t stream) {
    const float* x     = (const float*)d_in[0];
    const int*   ei    = (const int*)d_in[1];
    const int*   batch = (const int*)d_in[2];
    const float* W1    = (const float*)d_in[3];
    const float* b1    = (const float*)d_in[4];
    const float* W2    = (const float*)d_in[5];
    const float* b2    = (const float*)d_in[6];
    const float* Wl    = (const float*)d_in[7];
    const float* bl    = (const float*)d_in[8];

    const int N = in_sizes[0] / 3;
    const int E = in_sizes[1] / 2;
    const int* src = ei;
    const int* dst = ei + E;
    const int NBIN = (N + GN - 1) >> BSH2;        // coarse bins (<= 256)
    const int CH   = (E + NB2 - 1) / NB2;         // edges per chunk
    const int L    = NBIN * NB2;                  // histogram length

    char* w = (char*)d_ws;
    int*      row_ptr = (int*)w;      w += (size_t)(N + 4) * 4;
    float*    dinv    = (float*)w;    w += (size_t)N * 4;
    int*      histT   = (int*)w;      w += (size_t)(L + 4) * 4;  // +1 total slot
    int*      tmp2    = (int*)w;      w += (size_t)L * 4;
    int*      part2   = (int*)w;      w += (size_t)SCAN_B * 4;
    unsigned* binned  = (unsigned*)w; w += (size_t)(E + 16) * 4;
    int*      csr     = (int*)w;      w += (size_t)E * 4;
    float4*   xd      = (float4*)w;   w += (size_t)N * 16;
    __half*   g1h     = (__half*)w;   w += ((size_t)N * 32 + 15) & ~(size_t)15;
    float*    pooled  = (float*)w;    w += (size_t)NG * 32 * 4;
    float*    cnt     = (float*)w;    w += (size_t)NG * 4;

    const int B = 256;
    const int NBl = (L + SCAN_B - 1) / SCAN_B;

    k_hist<<<NB2, SCB, 0, stream>>>(dst, histT, E, CH, NBIN);
    k_scanA<<<NBl, SCAN_B, 0, stream>>>(histT, tmp2, part2, L);
    k_scanB<<<1, SCAN_B, 0, stream>>>(part2, NBl);
    k_applyT<<<(L + B - 1) / B, B, 0, stream>>>(tmp2, part2, histT, L, pooled, cnt);
    k_scatter<<<NB2, 1024, 0, stream>>>(src, dst, histT, binned, E, CH, NBIN);
    k_csr4<<<NBIN, 1024, 0, stream>>>(binned, histT, row_ptr, dinv, x, xd, csr, N, NBIN);

    k_ga<<<((size_t)N * 8 + B - 1) / B, B, 0, stream>>>(row_ptr, csr, xd, dinv, W1, b1, g1h, N);
    k_gb<<<((size_t)N * 8 + B - 1) / B, B, 0, stream>>>(row_ptr, csr, g1h, dinv, W2, b2, batch,
                                                        pooled, cnt, N);
    k_out<<<(NG * 3 + B - 1) / B, B, 0, stream>>>(pooled, cnt, Wl, bl, (float*)d_out);
}